// Round 12
// baseline (359.454 us; speedup 1.0000x reference)
//
#include <hip/hip_runtime.h>
#include <hip/hip_bf16.h>

#define NH 8
#define NF 16
#define NIN 256
#define HF 128    // NH*NF
#define CAP 3072  // 64-node bucket window capacity (counts ~2048+-45, max ~2230)
#define BCH 4096  // edges per bin block

typedef __attribute__((ext_vector_type(8))) short bf16x8;
typedef __attribute__((ext_vector_type(4))) float f32x4;

__device__ __forceinline__ unsigned short f2bf(float f) {
    union { float f; unsigned int u; } v; v.f = f;
    unsigned int r = v.u + 0x7FFFu + ((v.u >> 16) & 1u);
    return (unsigned short)(r >> 16);
}
__device__ __forceinline__ float bf2f(unsigned short b) {
    union { unsigned int u; float f; } v; v.u = ((unsigned int)b) << 16;
    return v.f;
}

// ---------------- MFMA GEMM: featb[n][128] = bf16( x @ W ), split-bf16 ----------------
// epilogue fused: el[n][h], er[n][h] from fp32 accumulators via shfl reduce.
#define GROWS 128
__global__ __launch_bounds__(256) void gemm_mfma(const float* __restrict__ A,
                                                 const float* __restrict__ W,
                                                 const float* __restrict__ attn_l,
                                                 const float* __restrict__ attn_r,
                                                 unsigned short* __restrict__ featb,
                                                 float* __restrict__ el,
                                                 float* __restrict__ er, int M) {
    __shared__ unsigned short AsH[32][264];
    __shared__ unsigned short AsL[32][264];
    const int tid = threadIdx.x;
    const int wave = tid >> 6, lane = tid & 63;
    const int quad = lane >> 4, lq = lane & 15;
    const int row0 = blockIdx.x * GROWS;

    bf16x8 bfrag[8][2];
#pragma unroll
    for (int h2 = 0; h2 < 2; h2++) {
        const int col = (wave * 2 + h2) * 16 + lq;
#pragma unroll
        for (int kk = 0; kk < 8; kk++) {
            const int kb = kk * 32 + quad * 8;
            bf16x8 f;
#pragma unroll
            for (int j = 0; j < 8; j++)
                f[j] = (short)f2bf(W[(size_t)(kb + j) * HF + col]);
            bfrag[kk][h2] = f;
        }
    }
    const float al0 = attn_l[(wave * 2 + 0) * 16 + lq];
    const float al1 = attn_l[(wave * 2 + 1) * 16 + lq];
    const float ar0 = attn_r[(wave * 2 + 0) * 16 + lq];
    const float ar1 = attn_r[(wave * 2 + 1) * 16 + lq];

    const int srow = tid >> 3;

    for (int c = 0; c < 4; c++) {
        const int crow0 = row0 + c * 32;
        __syncthreads();
#pragma unroll
        for (int i = 0; i < 8; i++) {
            const int col = ((tid & 7) + i * 8) * 4;
            const int gr = crow0 + srow;
            float4 v = make_float4(0.f, 0.f, 0.f, 0.f);
            if (gr < M) v = *(const float4*)&A[(size_t)gr * NIN + col];
            const unsigned short h0 = f2bf(v.x), h1 = f2bf(v.y),
                                 h2b = f2bf(v.z), h3 = f2bf(v.w);
            *(ushort4*)&AsH[srow][col] = make_ushort4(h0, h1, h2b, h3);
            *(ushort4*)&AsL[srow][col] =
                make_ushort4(f2bf(v.x - bf2f(h0)), f2bf(v.y - bf2f(h1)),
                             f2bf(v.z - bf2f(h2b)), f2bf(v.w - bf2f(h3)));
        }
        __syncthreads();
#pragma unroll
        for (int s = 0; s < 2; s++) {
            f32x4 acc0 = {0.f, 0.f, 0.f, 0.f};
            f32x4 acc1 = {0.f, 0.f, 0.f, 0.f};
            const int ar = s * 16 + lq;
#pragma unroll
            for (int kk = 0; kk < 8; kk++) {
                const bf16x8 ah = *(const bf16x8*)&AsH[ar][kk * 32 + quad * 8];
                const bf16x8 al = *(const bf16x8*)&AsL[ar][kk * 32 + quad * 8];
                acc0 = __builtin_amdgcn_mfma_f32_16x16x32_bf16(ah, bfrag[kk][0], acc0, 0, 0, 0);
                acc1 = __builtin_amdgcn_mfma_f32_16x16x32_bf16(ah, bfrag[kk][1], acc1, 0, 0, 0);
                acc0 = __builtin_amdgcn_mfma_f32_16x16x32_bf16(al, bfrag[kk][0], acc0, 0, 0, 0);
                acc1 = __builtin_amdgcn_mfma_f32_16x16x32_bf16(al, bfrag[kk][1], acc1, 0, 0, 0);
            }
#pragma unroll
            for (int r = 0; r < 4; r++) {
                const int gr = crow0 + s * 16 + quad * 4 + r;
                float pl0 = acc0[r] * al0, pr0 = acc0[r] * ar0;
                float pl1 = acc1[r] * al1, pr1 = acc1[r] * ar1;
#pragma unroll
                for (int m = 1; m < 16; m <<= 1) {
                    pl0 += __shfl_xor(pl0, m, 64);
                    pr0 += __shfl_xor(pr0, m, 64);
                    pl1 += __shfl_xor(pl1, m, 64);
                    pr1 += __shfl_xor(pr1, m, 64);
                }
                if (gr < M) {
                    featb[(size_t)gr * HF + (wave * 2 + 0) * 16 + lq] = f2bf(acc0[r]);
                    featb[(size_t)gr * HF + (wave * 2 + 1) * 16 + lq] = f2bf(acc1[r]);
                    if (lq == 0) {
                        el[(size_t)gr * NH + wave * 2 + 0] = pl0;
                        el[(size_t)gr * NH + wave * 2 + 1] = pl1;
                        er[(size_t)gr * NH + wave * 2 + 0] = pr0;
                        er[(size_t)gr * NH + wave * 2 + 1] = pr1;
                    }
                }
            }
        }
    }
}

// ---------------- bin: block-local counting sort over 64-node buckets -----------
// COALESCED dense output binned[blk*BCH+i]; runtab[blk*NB+b] = off | cnt<<16.
__global__ __launch_bounds__(256) void bin_kernel(const int* __restrict__ src,
                                                  const int* __restrict__ dst,
                                                  unsigned int* __restrict__ binned,
                                                  unsigned int* __restrict__ runtab,
                                                  int E, int NB) {
    __shared__ unsigned int hist[784];
    __shared__ unsigned int offs[784];
    __shared__ unsigned short lpos[BCH];
    __shared__ unsigned int obuf[BCH];
    __shared__ int dcache[BCH];
    __shared__ unsigned int wsum[4];
    __shared__ unsigned int sbase;
    const int blk = blockIdx.x, t = threadIdx.x;
    const int base = blk * BCH;
    const int cnt = min(BCH, E - base);
    const int lane = t & 63, w = t >> 6;
    for (int b = t; b < NB; b += 256) hist[b] = 0;
    for (int i = t; i < cnt; i += 256) dcache[i] = dst[base + i];
    if (t == 0) sbase = 0;
    __syncthreads();
    for (int i = t; i < cnt; i += 256)
        lpos[i] = (unsigned short)atomicAdd(&hist[dcache[i] >> 6], 1u);
    __syncthreads();
    // block-wide exclusive scan over NB (<=784) bucket counts, 256 at a time
    for (int c0 = 0; c0 < NB; c0 += 256) {
        const int idx = c0 + t;
        const unsigned int v = (idx < NB) ? hist[idx] : 0;
        unsigned int incl = v;
#pragma unroll
        for (int off = 1; off < 64; off <<= 1) {
            const unsigned int x = __shfl_up(incl, off, 64);
            if (lane >= off) incl += x;
        }
        if (lane == 63) wsum[w] = incl;
        __syncthreads();
        unsigned int wbase = 0;
        for (int k = 0; k < w; k++) wbase += wsum[k];
        const unsigned int tot = wsum[0] + wsum[1] + wsum[2] + wsum[3];
        const unsigned int excl = sbase + wbase + incl - v;
        if (idx < NB) {
            offs[idx] = excl;
            runtab[(size_t)blk * NB + idx] = excl | (v << 16);
        }
        __syncthreads();
        if (t == 0) sbase += tot;
        __syncthreads();
    }
    for (int i = t; i < cnt; i += 256) {
        const int d = dcache[i];
        obuf[offs[d >> 6] + lpos[i]] =
            (unsigned int)src[base + i] | ((unsigned int)(d & 63) << 16);
    }
    __syncthreads();
    for (int i = t; i < cnt; i += 256) binned[(size_t)base + i] = obuf[i];
}

// ---------------- prefix: per bucket, running base over block-runs ----------------
// combo[b*(nbb+1)+blk] = run_off (12b) | bucket_local_base << 12; cnt = next.base - base
// NOTE: mask off to 12 bits — empty runs in a full block can carry excl==4096 (bit 12),
// which would corrupt the base field (this was R11's correctness bug).
__global__ __launch_bounds__(256) void prefix_kernel(const unsigned int* __restrict__ runtab,
                                                     unsigned int* __restrict__ combo,
                                                     int NB, int nbb) {
    const int b = blockIdx.x * 256 + threadIdx.x;
    if (b >= NB) return;
    unsigned int acc = 0;
    unsigned int* cb = &combo[(size_t)b * (nbb + 1)];
    for (int blk = 0; blk < nbb; blk++) {
        const unsigned int e = runtab[(size_t)blk * NB + b];
        cb[blk] = (e & 0xFFFu) | (acc << 12);
        acc += (e >> 16);
    }
    cb[nbb] = (acc << 12);
}

// ---------------- csr: thread-per-run gather -> LDS sort -> coalesced out ----------
__global__ __launch_bounds__(256) void csr_kernel(const unsigned int* __restrict__ binned,
                                                  const unsigned int* __restrict__ combo,
                                                  int* __restrict__ nodeinfo,
                                                  unsigned short* __restrict__ srcsw,
                                                  int N, int nbb) {
    __shared__ unsigned int eary[CAP];
    __shared__ unsigned short sSrc[CAP];
    __shared__ int len[64], cur[64];
    __shared__ int tot_s;
    const int b = blockIdx.x, t = threadIdx.x;
    const int node0 = b << 6;
    const unsigned int* cb = &combo[(size_t)b * (nbb + 1)];
    // gather this bucket's runs (contiguous ~5-entry chunks) into LDS
    for (int r = t; r < nbb; r += 256) {
        const unsigned int c0 = cb[r], c1 = cb[r + 1];
        const int off = (int)(c0 & 0xFFFu);
        const int pb = (int)(c0 >> 12);
        const int rc = (int)(c1 >> 12) - pb;
        const unsigned int* bp = &binned[(size_t)r * BCH + off];
        for (int j = 0; j < rc; j++) eary[pb + j] = bp[j];
    }
    if (t < 64) len[t] = 0;
    if (t == 0) tot_s = (int)(cb[nbb] >> 12);
    __syncthreads();
    const int tot = tot_s;
    for (int i = t; i < tot; i += 256) atomicAdd(&len[eary[i] >> 16], 1);
    __syncthreads();
    if (t < 64) {  // single-wave prefix over 64 node lengths
        const int v = len[t];
        int incl = v;
#pragma unroll
        for (int off = 1; off < 64; off <<= 1) {
            const int x = __shfl_up(incl, off, 64);
            if (t >= off) incl += x;
        }
        const int excl = incl - v;
        cur[t] = excl;
        if (node0 + t < N) nodeinfo[node0 + t] = excl | (v << 16);
    }
    __syncthreads();
    for (int i = t; i < tot; i += 256) {
        const unsigned int p = eary[i];
        const int pos = atomicAdd(&cur[p >> 16], 1);
        sSrc[pos] = (unsigned short)(p & 0xFFFFu);
    }
    __syncthreads();
    unsigned short* sw = &srcsw[(size_t)b * CAP];
    for (int i = t; i < tot; i += 256) sw[i] = sSrc[i];
}

// ---------------- fused aggregation: softmax + weighted sum + bias + head-mean ----
// block = 128 thr per node; 32-edge rounds; fixed-16 unrolled pipelined gathers.
__global__ __launch_bounds__(128) void agg_kernel(const int* __restrict__ nodeinfo,
                                                  const unsigned short* __restrict__ srcsw,
                                                  const float* __restrict__ el,
                                                  const float* __restrict__ er,
                                                  const unsigned short* __restrict__ featb,
                                                  const float* __restrict__ bias,
                                                  float* __restrict__ out) {
    const int n = blockIdx.x;
    const int tid = threadIdx.x;
    __shared__ float lds_sc[32][8];
    __shared__ int lds_src[32];
    __shared__ float lds_ps[128];
    __shared__ float lds_s[8];
    __shared__ float2 lds_acc[2][64];
    __shared__ float2 lds_v[8][8];

    const int info = nodeinfo[n];
    const int begin = (n >> 6) * CAP + (info & 0xFFFF);
    const int end = begin + (info >> 16);
    const int hA = tid & 7, eA = tid >> 3;     // phase A: 16 edges x 8 heads
    const float er_h = er[(size_t)n * NH + hA];
    const int w = tid >> 6, lane = tid & 63;
    const int hB = lane >> 3, fB2 = lane & 7;  // phase B: 8 heads x 8 feat-pairs

    float2 acc = make_float2(0.f, 0.f);
    float psum = 0.f;
    for (int base = begin; base < end; base += 32) {
        const int cn = min(32, end - base);
#pragma unroll
        for (int rep = 0; rep < 2; rep++) {
            const int ei = eA + rep * 16;
            if (ei < cn) {
                const int si = (int)srcsw[base + ei];
                if (hA == 0) lds_src[ei] = si;
                float v = el[(size_t)si * NH + hA] + er_h;
                v = v > 0.f ? v : 0.2f * v;
                const float sc = __expf(v);
                lds_sc[ei][hA] = sc;
                psum += sc;
            }
        }
        __syncthreads();
        // wave w gathers edges w*16 .. w*16+15: 16 independent 4B loads in flight
        unsigned int fv[16];
#pragma unroll
        for (int j = 0; j < 16; j++) {
            const int ej = w * 16 + j;
            const int sj = lds_src[ej];
            fv[j] = (ej < cn)
                        ? *(const unsigned int*)&featb[(size_t)sj * HF + hB * 16 + fB2 * 2]
                        : 0u;
        }
#pragma unroll
        for (int j = 0; j < 16; j++) {
            const int ej = w * 16 + j;
            const float sc = (ej < cn) ? lds_sc[ej][hB] : 0.f;
            acc.x = fmaf(sc, bf2f((unsigned short)(fv[j] & 0xFFFFu)), acc.x);
            acc.y = fmaf(sc, bf2f((unsigned short)(fv[j] >> 16)), acc.y);
        }
        __syncthreads();
    }

    lds_ps[tid] = psum;
    lds_acc[w][lane] = acc;
    __syncthreads();
    if (tid < 8) {
        float s = 0.f;
#pragma unroll
        for (int k = 0; k < 16; k++) s += lds_ps[k * 8 + tid];
        lds_s[tid] = fmaxf(s, 1e-9f);
    }
    __syncthreads();
    if (tid < 64) {
        const float2 t0 = lds_acc[0][tid], t1 = lds_acc[1][tid];
        const float inv = 1.f / lds_s[hB];
        float2 val;
        val.x = (t0.x + t1.x) * inv + bias[hB * 16 + fB2 * 2];
        val.y = (t0.y + t1.y) * inv + bias[hB * 16 + fB2 * 2 + 1];
        lds_v[hB][fB2] = val;
    }
    __syncthreads();
    if (tid < 8) {
        float2 o = make_float2(0.f, 0.f);
#pragma unroll
        for (int h = 0; h < 8; h++) {
            const float2 v = lds_v[h][tid];
            o.x += v.x; o.y += v.y;
        }
        o.x *= 0.125f; o.y *= 0.125f;
        *(float2*)&out[(size_t)n * 16 + tid * 2] = o;
    }
}

extern "C" void kernel_launch(void* const* d_in, const int* in_sizes, int n_in,
                              void* d_out, int out_size, void* d_ws, size_t ws_size,
                              hipStream_t stream) {
    const float* x      = (const float*)d_in[0];
    const float* W      = (const float*)d_in[1];
    const float* attn_l = (const float*)d_in[2];
    const float* attn_r = (const float*)d_in[3];
    const float* bias   = (const float*)d_in[4];
    const int*   src    = (const int*)d_in[5];
    const int*   dst    = (const int*)d_in[6];
    float* out = (float*)d_out;

    const int N = in_sizes[0] / NIN;
    const int E = in_sizes[5];
    const int NB = (N + 63) >> 6;           // 782 buckets of 64 nodes
    const int nbb = (E + BCH - 1) / BCH;    // 391 bin blocks

    // workspace carve-up
    char* w = (char*)d_ws;
    unsigned short* featb = (unsigned short*)w; w += (size_t)N * HF * 2;
    float* el     = (float*)w; w += (size_t)N * NH * 4;
    float* er     = (float*)w; w += (size_t)N * NH * 4;
    int* nodeinfo = (int*)w;   w += (size_t)N * 4;
    unsigned int* binned = (unsigned int*)w; w += (size_t)nbb * BCH * 4;
    unsigned int* runtab = (unsigned int*)w; w += (size_t)nbb * NB * 4;
    unsigned int* combo  = (unsigned int*)w; w += (size_t)NB * (nbb + 1) * 4;
    unsigned short* srcsw = (unsigned short*)w;

    gemm_mfma<<<(N + GROWS - 1) / GROWS, 256, 0, stream>>>(x, W, attn_l, attn_r,
                                                           featb, el, er, N);
    bin_kernel<<<nbb, 256, 0, stream>>>(src, dst, binned, runtab, E, NB);
    prefix_kernel<<<(NB + 255) / 256, 256, 0, stream>>>(runtab, combo, NB, nbb);
    csr_kernel<<<NB, 256, 0, stream>>>(binned, combo, nodeinfo, srcsw, N, nbb);
    agg_kernel<<<N, 128, 0, stream>>>(nodeinfo, srcsw, el, er, featb, bias, out);
}

// Round 13
// 228.036 us; speedup vs baseline: 1.5763x; 1.5763x over previous
//
#include <hip/hip_runtime.h>
#include <hip/hip_bf16.h>

#define NH 8
#define NF 16
#define NIN 256
#define HF 128    // NH*NF
#define CAP 3072  // 64-node bucket window capacity (counts ~2048+-45, max ~2230)
#define BCH 4096  // edges per bin block

typedef __attribute__((ext_vector_type(8))) short bf16x8;
typedef __attribute__((ext_vector_type(4))) float f32x4;

__device__ __forceinline__ unsigned short f2bf(float f) {
    union { float f; unsigned int u; } v; v.f = f;
    unsigned int r = v.u + 0x7FFFu + ((v.u >> 16) & 1u);
    return (unsigned short)(r >> 16);
}
__device__ __forceinline__ float bf2f(unsigned short b) {
    union { unsigned int u; float f; } v; v.u = ((unsigned int)b) << 16;
    return v.f;
}

// ---------------- MFMA GEMM: featb[n][128] = bf16( x @ W ), split-bf16 ----------------
// epilogue fused: el[n][h], er[n][h] from fp32 accumulators via shfl reduce.
#define GROWS 128
__global__ __launch_bounds__(256) void gemm_mfma(const float* __restrict__ A,
                                                 const float* __restrict__ W,
                                                 const float* __restrict__ attn_l,
                                                 const float* __restrict__ attn_r,
                                                 unsigned short* __restrict__ featb,
                                                 float* __restrict__ el,
                                                 float* __restrict__ er, int M) {
    __shared__ unsigned short AsH[32][264];
    __shared__ unsigned short AsL[32][264];
    const int tid = threadIdx.x;
    const int wave = tid >> 6, lane = tid & 63;
    const int quad = lane >> 4, lq = lane & 15;
    const int row0 = blockIdx.x * GROWS;

    bf16x8 bfrag[8][2];
#pragma unroll
    for (int h2 = 0; h2 < 2; h2++) {
        const int col = (wave * 2 + h2) * 16 + lq;
#pragma unroll
        for (int kk = 0; kk < 8; kk++) {
            const int kb = kk * 32 + quad * 8;
            bf16x8 f;
#pragma unroll
            for (int j = 0; j < 8; j++)
                f[j] = (short)f2bf(W[(size_t)(kb + j) * HF + col]);
            bfrag[kk][h2] = f;
        }
    }
    const float al0 = attn_l[(wave * 2 + 0) * 16 + lq];
    const float al1 = attn_l[(wave * 2 + 1) * 16 + lq];
    const float ar0 = attn_r[(wave * 2 + 0) * 16 + lq];
    const float ar1 = attn_r[(wave * 2 + 1) * 16 + lq];

    const int srow = tid >> 3;

    for (int c = 0; c < 4; c++) {
        const int crow0 = row0 + c * 32;
        __syncthreads();
#pragma unroll
        for (int i = 0; i < 8; i++) {
            const int col = ((tid & 7) + i * 8) * 4;
            const int gr = crow0 + srow;
            float4 v = make_float4(0.f, 0.f, 0.f, 0.f);
            if (gr < M) v = *(const float4*)&A[(size_t)gr * NIN + col];
            const unsigned short h0 = f2bf(v.x), h1 = f2bf(v.y),
                                 h2b = f2bf(v.z), h3 = f2bf(v.w);
            *(ushort4*)&AsH[srow][col] = make_ushort4(h0, h1, h2b, h3);
            *(ushort4*)&AsL[srow][col] =
                make_ushort4(f2bf(v.x - bf2f(h0)), f2bf(v.y - bf2f(h1)),
                             f2bf(v.z - bf2f(h2b)), f2bf(v.w - bf2f(h3)));
        }
        __syncthreads();
#pragma unroll
        for (int s = 0; s < 2; s++) {
            f32x4 acc0 = {0.f, 0.f, 0.f, 0.f};
            f32x4 acc1 = {0.f, 0.f, 0.f, 0.f};
            const int ar = s * 16 + lq;
#pragma unroll
            for (int kk = 0; kk < 8; kk++) {
                const bf16x8 ah = *(const bf16x8*)&AsH[ar][kk * 32 + quad * 8];
                const bf16x8 al = *(const bf16x8*)&AsL[ar][kk * 32 + quad * 8];
                acc0 = __builtin_amdgcn_mfma_f32_16x16x32_bf16(ah, bfrag[kk][0], acc0, 0, 0, 0);
                acc1 = __builtin_amdgcn_mfma_f32_16x16x32_bf16(ah, bfrag[kk][1], acc1, 0, 0, 0);
                acc0 = __builtin_amdgcn_mfma_f32_16x16x32_bf16(al, bfrag[kk][0], acc0, 0, 0, 0);
                acc1 = __builtin_amdgcn_mfma_f32_16x16x32_bf16(al, bfrag[kk][1], acc1, 0, 0, 0);
            }
#pragma unroll
            for (int r = 0; r < 4; r++) {
                const int gr = crow0 + s * 16 + quad * 4 + r;
                float pl0 = acc0[r] * al0, pr0 = acc0[r] * ar0;
                float pl1 = acc1[r] * al1, pr1 = acc1[r] * ar1;
#pragma unroll
                for (int m = 1; m < 16; m <<= 1) {
                    pl0 += __shfl_xor(pl0, m, 64);
                    pr0 += __shfl_xor(pr0, m, 64);
                    pl1 += __shfl_xor(pl1, m, 64);
                    pr1 += __shfl_xor(pr1, m, 64);
                }
                if (gr < M) {
                    featb[(size_t)gr * HF + (wave * 2 + 0) * 16 + lq] = f2bf(acc0[r]);
                    featb[(size_t)gr * HF + (wave * 2 + 1) * 16 + lq] = f2bf(acc1[r]);
                    if (lq == 0) {
                        el[(size_t)gr * NH + wave * 2 + 0] = pl0;
                        el[(size_t)gr * NH + wave * 2 + 1] = pl1;
                        er[(size_t)gr * NH + wave * 2 + 0] = pr0;
                        er[(size_t)gr * NH + wave * 2 + 1] = pr1;
                    }
                }
            }
        }
    }
}

// ---------------- bin: block-local counting sort over 64-node buckets -----------
// COALESCED dense output binned[blk*BCH+i]; runtab[blk*NB+b] = off | cnt<<16.
__global__ __launch_bounds__(256) void bin_kernel(const int* __restrict__ src,
                                                  const int* __restrict__ dst,
                                                  unsigned int* __restrict__ binned,
                                                  unsigned int* __restrict__ runtab,
                                                  int E, int NB) {
    __shared__ unsigned int hist[784];
    __shared__ unsigned int offs[784];
    __shared__ unsigned short lpos[BCH];
    __shared__ unsigned int obuf[BCH];
    __shared__ int dcache[BCH];
    __shared__ unsigned int wsum[4];
    __shared__ unsigned int sbase;
    const int blk = blockIdx.x, t = threadIdx.x;
    const int base = blk * BCH;
    const int cnt = min(BCH, E - base);
    const int lane = t & 63, w = t >> 6;
    for (int b = t; b < NB; b += 256) hist[b] = 0;
    for (int i = t; i < cnt; i += 256) dcache[i] = dst[base + i];
    if (t == 0) sbase = 0;
    __syncthreads();
    for (int i = t; i < cnt; i += 256)
        lpos[i] = (unsigned short)atomicAdd(&hist[dcache[i] >> 6], 1u);
    __syncthreads();
    // block-wide exclusive scan over NB (<=784) bucket counts, 256 at a time
    for (int c0 = 0; c0 < NB; c0 += 256) {
        const int idx = c0 + t;
        const unsigned int v = (idx < NB) ? hist[idx] : 0;
        unsigned int incl = v;
#pragma unroll
        for (int off = 1; off < 64; off <<= 1) {
            const unsigned int x = __shfl_up(incl, off, 64);
            if (lane >= off) incl += x;
        }
        if (lane == 63) wsum[w] = incl;
        __syncthreads();
        unsigned int wbase = 0;
        for (int k = 0; k < w; k++) wbase += wsum[k];
        const unsigned int tot = wsum[0] + wsum[1] + wsum[2] + wsum[3];
        const unsigned int excl = sbase + wbase + incl - v;
        if (idx < NB) {
            offs[idx] = excl;
            runtab[(size_t)blk * NB + idx] = excl | (v << 16);
        }
        __syncthreads();
        if (t == 0) sbase += tot;
        __syncthreads();
    }
    for (int i = t; i < cnt; i += 256) {
        const int d = dcache[i];
        obuf[offs[d >> 6] + lpos[i]] =
            (unsigned int)src[base + i] | ((unsigned int)(d & 63) << 16);
    }
    __syncthreads();
    for (int i = t; i < cnt; i += 256) binned[(size_t)base + i] = obuf[i];
}

// ---------------- csr: column-read runtab + in-block prefix + gather + LDS sort -----
// One 256-thread block per bucket. Replaces R12's latency-bound prefix_kernel:
// the 391-run prefix is done here with a block-wide shfl scan (parallel per bucket).
__global__ __launch_bounds__(256) void csr_kernel(const unsigned int* __restrict__ binned,
                                                  const unsigned int* __restrict__ runtab,
                                                  int* __restrict__ nodeinfo,
                                                  unsigned short* __restrict__ srcsw,
                                                  int N, int NB, int nbb) {
    __shared__ unsigned int eary[CAP];
    __shared__ unsigned short sSrc[CAP];
    __shared__ unsigned short roff[512];
    __shared__ unsigned short rcntl[512];
    __shared__ int rbase[512];
    __shared__ int len[64], cur[64];
    __shared__ unsigned int wsum[4];
    __shared__ unsigned int sbase;
    const int b = blockIdx.x, t = threadIdx.x;
    const int node0 = b << 6;
    const int lane = t & 63, w = t >> 6;
    if (t == 0) sbase = 0;
    __syncthreads();
    // load runtab column + block-wide exclusive scan over run counts
    for (int c0 = 0; c0 < nbb; c0 += 256) {
        const int r = c0 + t;
        const unsigned int e = (r < nbb) ? runtab[(size_t)r * NB + b] : 0;
        const unsigned int v = e >> 16;
        unsigned int incl = v;
#pragma unroll
        for (int off = 1; off < 64; off <<= 1) {
            const unsigned int x = __shfl_up(incl, off, 64);
            if (lane >= off) incl += x;
        }
        if (lane == 63) wsum[w] = incl;
        __syncthreads();
        unsigned int wbase = 0;
        for (int k = 0; k < w; k++) wbase += wsum[k];
        const unsigned int tot = wsum[0] + wsum[1] + wsum[2] + wsum[3];
        if (r < nbb) {
            roff[r] = (unsigned short)(e & 0xFFFFu);
            rcntl[r] = (unsigned short)v;
            rbase[r] = (int)(sbase + wbase + incl - v);
        }
        __syncthreads();
        if (t == 0) sbase += tot;
        __syncthreads();
    }
    const int tot = (int)sbase;
    // gather this bucket's runs (contiguous ~5-entry chunks) into LDS
    for (int r = t; r < nbb; r += 256) {
        const int off = (int)roff[r];
        const int pb = rbase[r];
        const int rc = (int)rcntl[r];
        const unsigned int* bp = &binned[(size_t)r * BCH + off];
        for (int j = 0; j < rc; j++) eary[pb + j] = bp[j];
    }
    if (t < 64) len[t] = 0;
    __syncthreads();
    for (int i = t; i < tot; i += 256) atomicAdd(&len[eary[i] >> 16], 1);
    __syncthreads();
    if (t < 64) {  // single-wave prefix over 64 node lengths
        const int v = len[t];
        int incl = v;
#pragma unroll
        for (int off = 1; off < 64; off <<= 1) {
            const int x = __shfl_up(incl, off, 64);
            if (t >= off) incl += x;
        }
        const int excl = incl - v;
        cur[t] = excl;
        if (node0 + t < N) nodeinfo[node0 + t] = excl | (v << 16);
    }
    __syncthreads();
    for (int i = t; i < tot; i += 256) {
        const unsigned int p = eary[i];
        const int pos = atomicAdd(&cur[p >> 16], 1);
        sSrc[pos] = (unsigned short)(p & 0xFFFFu);
    }
    __syncthreads();
    unsigned short* sw = &srcsw[(size_t)b * CAP];
    for (int i = t; i < tot; i += 256) sw[i] = sSrc[i];
}

// ---------------- fused aggregation: softmax + weighted sum + bias + head-mean ----
// block = 128 thr per node; 32-edge rounds; fixed-16 unrolled pipelined gathers.
__global__ __launch_bounds__(128) void agg_kernel(const int* __restrict__ nodeinfo,
                                                  const unsigned short* __restrict__ srcsw,
                                                  const float* __restrict__ el,
                                                  const float* __restrict__ er,
                                                  const unsigned short* __restrict__ featb,
                                                  const float* __restrict__ bias,
                                                  float* __restrict__ out) {
    const int n = blockIdx.x;
    const int tid = threadIdx.x;
    __shared__ float lds_sc[32][8];
    __shared__ int lds_src[32];
    __shared__ float lds_ps[128];
    __shared__ float lds_s[8];
    __shared__ float2 lds_acc[2][64];
    __shared__ float2 lds_v[8][8];

    const int info = nodeinfo[n];
    const int begin = (n >> 6) * CAP + (info & 0xFFFF);
    const int end = begin + (info >> 16);
    const int hA = tid & 7, eA = tid >> 3;     // phase A: 16 edges x 8 heads
    const float er_h = er[(size_t)n * NH + hA];
    const int w = tid >> 6, lane = tid & 63;
    const int hB = lane >> 3, fB2 = lane & 7;  // phase B: 8 heads x 8 feat-pairs

    float2 acc = make_float2(0.f, 0.f);
    float psum = 0.f;
    for (int base = begin; base < end; base += 32) {
        const int cn = min(32, end - base);
#pragma unroll
        for (int rep = 0; rep < 2; rep++) {
            const int ei = eA + rep * 16;
            if (ei < cn) {
                const int si = (int)srcsw[base + ei];
                if (hA == 0) lds_src[ei] = si;
                float v = el[(size_t)si * NH + hA] + er_h;
                v = v > 0.f ? v : 0.2f * v;
                const float sc = __expf(v);
                lds_sc[ei][hA] = sc;
                psum += sc;
            }
        }
        __syncthreads();
        // wave w gathers edges w*16 .. w*16+15: 16 independent 4B loads in flight
        unsigned int fv[16];
#pragma unroll
        for (int j = 0; j < 16; j++) {
            const int ej = w * 16 + j;
            const int sj = lds_src[ej];
            fv[j] = (ej < cn)
                        ? *(const unsigned int*)&featb[(size_t)sj * HF + hB * 16 + fB2 * 2]
                        : 0u;
        }
#pragma unroll
        for (int j = 0; j < 16; j++) {
            const int ej = w * 16 + j;
            const float sc = (ej < cn) ? lds_sc[ej][hB] : 0.f;
            acc.x = fmaf(sc, bf2f((unsigned short)(fv[j] & 0xFFFFu)), acc.x);
            acc.y = fmaf(sc, bf2f((unsigned short)(fv[j] >> 16)), acc.y);
        }
        __syncthreads();
    }

    lds_ps[tid] = psum;
    lds_acc[w][lane] = acc;
    __syncthreads();
    if (tid < 8) {
        float s = 0.f;
#pragma unroll
        for (int k = 0; k < 16; k++) s += lds_ps[k * 8 + tid];
        lds_s[tid] = fmaxf(s, 1e-9f);
    }
    __syncthreads();
    if (tid < 64) {
        const float2 t0 = lds_acc[0][tid], t1 = lds_acc[1][tid];
        const float inv = 1.f / lds_s[hB];
        float2 val;
        val.x = (t0.x + t1.x) * inv + bias[hB * 16 + fB2 * 2];
        val.y = (t0.y + t1.y) * inv + bias[hB * 16 + fB2 * 2 + 1];
        lds_v[hB][fB2] = val;
    }
    __syncthreads();
    if (tid < 8) {
        float2 o = make_float2(0.f, 0.f);
#pragma unroll
        for (int h = 0; h < 8; h++) {
            const float2 v = lds_v[h][tid];
            o.x += v.x; o.y += v.y;
        }
        o.x *= 0.125f; o.y *= 0.125f;
        *(float2*)&out[(size_t)n * 16 + tid * 2] = o;
    }
}

extern "C" void kernel_launch(void* const* d_in, const int* in_sizes, int n_in,
                              void* d_out, int out_size, void* d_ws, size_t ws_size,
                              hipStream_t stream) {
    const float* x      = (const float*)d_in[0];
    const float* W      = (const float*)d_in[1];
    const float* attn_l = (const float*)d_in[2];
    const float* attn_r = (const float*)d_in[3];
    const float* bias   = (const float*)d_in[4];
    const int*   src    = (const int*)d_in[5];
    const int*   dst    = (const int*)d_in[6];
    float* out = (float*)d_out;

    const int N = in_sizes[0] / NIN;
    const int E = in_sizes[5];
    const int NB = (N + 63) >> 6;           // 782 buckets of 64 nodes
    const int nbb = (E + BCH - 1) / BCH;    // 391 bin blocks

    // workspace carve-up
    char* w = (char*)d_ws;
    unsigned short* featb = (unsigned short*)w; w += (size_t)N * HF * 2;
    float* el     = (float*)w; w += (size_t)N * NH * 4;
    float* er     = (float*)w; w += (size_t)N * NH * 4;
    int* nodeinfo = (int*)w;   w += (size_t)N * 4;
    unsigned int* binned = (unsigned int*)w; w += (size_t)nbb * BCH * 4;
    unsigned int* runtab = (unsigned int*)w; w += (size_t)nbb * NB * 4;
    unsigned short* srcsw = (unsigned short*)w;

    gemm_mfma<<<(N + GROWS - 1) / GROWS, 256, 0, stream>>>(x, W, attn_l, attn_r,
                                                           featb, el, er, N);
    bin_kernel<<<nbb, 256, 0, stream>>>(src, dst, binned, runtab, E, NB);
    csr_kernel<<<NB, 256, 0, stream>>>(binned, runtab, nodeinfo, srcsw, N, NB, nbb);
    agg_kernel<<<N, 128, 0, stream>>>(nodeinfo, srcsw, el, er, featb, bias, out);
}